// Round 5
// baseline (5979.681 us; speedup 1.0000x reference)
//
#include <hip/hip_runtime.h>

typedef unsigned int u32;

#define N_NODES 32768
#define N_EDGES 262144
#define PF 65   // LDS pitch (floats): 64 edges + 1 pad

// ---------- fp32 weight buffer layout (float offsets in d_ws) ----------
enum : int {
  OFF_RT_W   = 0,       // [64,128]
  OFF_RT_B   = 8192,    // [128]
  OFF_RIN_W  = 8320,    // [128,192]  (stored PERMUTED: col c -> (c%4)*48 + c/4)
  OFF_RIN_B  = 32896,   // [192]
  OFF_ROUT_W = 33088,   // [128,192]
  OFF_ROUT_B = 57664,   // [192]
  OFF_TP00   = 57856,   // [128,128]
  OFF_TP01   = 74240,   // [128,64]
  OFF_TP10   = 82432,   // [64,64]
  OFF_TP11   = 86528,   // [64,128]
  OFF_ACT_W1 = 94720,   // [64,64]
  OFF_ACT_B1 = 98816,   // [64]
  OFF_ACT_W2 = 98880,   // [64,64]
  OFF_ACT_B2 = 102976,  // [64]
  OFF_GATE_W1= 103040,  // [64,64]
  OFF_GATE_B1= 107136,  // [64]
  OFF_GATE_W2= 107200,  // [64,65]
  OFF_GATE_B2= 111360,  // [65]
  OFF_LSIG   = 111428,  // [10]
  OFF_VR_W   = 111440,  // [64,64]
  OFF_VR_B   = 115536,  // [64]
  OFF_SELF_WS= 115600,  // [128,128]
  OFF_SELF_BS= 131984,  // [128]
  OFF_SELF_WV= 132112,  // [64,64]
  NWF        = 136208
};
enum : int {
  ACC_S_OFF  = NWF,
  ACC_SG_OFF = ACC_S_OFF + N_NODES*128,
  ACC_VG_OFF = ACC_SG_OFF + N_NODES,
  ACC_V_OFF  = ACC_VG_OFF + N_NODES*64,
  ACC_END    = ACC_V_OFF + N_NODES*192
};

__device__ __forceinline__ float fsilu(float x){ return x/(1.f+__expf(-x)); }
__device__ __forceinline__ float fsig (float x){ return 1.f/(1.f+__expf(-x)); }

#define SQ3f     1.7320508075688772f
#define INV_SQ3f 0.5773502691896258f

__global__ void k_zero(float* __restrict__ p, int n){
  int t = blockIdx.x*256 + threadIdx.x;
  if (t < n) p[t] = 0.f;
}

// weight copy; tensor index 2 (rin_w) gets its columns permuted so that
// wave wv's owned cols {4i+wv} land contiguously at [48*wv, 48*wv+48)
struct WCopy { const float* src[24]; int n[24]; int off[24]; };

__global__ void k_copy(WCopy w, float* __restrict__ dst){
  int t = blockIdx.x*256 + threadIdx.x;
  for (int a=0;a<24;++a){
    int n = w.n[a];
    if (t < n){
      if (a == 2){
        int k = t/192, c = t%192;
        dst[w.off[a] + k*192 + (c&3)*48 + (c>>2)] = w.src[a][t];
      } else {
        dst[w.off[a]+t] = w.src[a][t];
      }
      return;
    }
    t -= n;
  }
}

// ---------------- edge kernel ----------------
// LDS arena: 224 channels x pitch 65 floats (58.2 KB)
// C_ES [0,64): edge_scalars, resident whole kernel
// C_T  [64,192): trunk (P1-P2), then recycled:
// C_XB [64,160): x chunks (96 max)     C_VN [64,128): |msg_v|
// C_T1 [128,192): act hidden           C_DOT[160,224): dot / later ge
constexpr int C_ES=0, C_T=64, C_XB=64, C_DOT=160, C_VN=64, C_T1=128, C_GE=160;

__launch_bounds__(256,2)
__global__ void k_edge(const float* __restrict__ h, const float* __restrict__ evec,
                       const float* __restrict__ es_g, const float* __restrict__ edist,
                       const int* __restrict__ src_idx, const int* __restrict__ dst_idx,
                       const int* __restrict__ etype, const float* __restrict__ wf,
                       float* __restrict__ acc_s, float* __restrict__ acc_sg,
                       float* __restrict__ acc_vg, float* __restrict__ acc_v)
{
  __shared__ float smf[224*PF];
  __shared__ float s_sgate[64];
  __shared__ int   s_src[64];

  const int tid  = threadIdx.x;
  const int lane = tid & 63;
  const int wv   = __builtin_amdgcn_readfirstlane(tid >> 6);
  const int e0   = blockIdx.x * 64;
  const int e    = e0 + lane;

  if (tid < 64) s_src[tid] = src_idx[e0 + tid];

  float y0,y1,y2;
  { float vx=evec[e*3], vy=evec[e*3+1], vz=evec[e*3+2];
    float rn = SQ3f * rsqrtf(vx*vx+vy*vy+vz*vz+1e-12f);
    y0=vx*rn; y1=vy*rn; y2=vz*rn; }

  // P0: stage edge_scalars (fp32, coalesced float4)
  for (int lin=tid; lin<1024; lin+=256){
    int row = lin>>4, c4 = lin&15;
    float4 v = reinterpret_cast<const float4*>(es_g)[(e0+row)*16 + c4];
    smf[(C_ES + c4*4+0)*PF + row] = v.x;
    smf[(C_ES + c4*4+1)*PF + row] = v.y;
    smf[(C_ES + c4*4+2)*PF + row] = v.z;
    smf[(C_ES + c4*4+3)*PF + row] = v.w;
  }
  __syncthreads();

  // P1: trunk = silu(es @ rt_w + rt_b), 32 ch/wave -> C_T
  { const int c0 = 32*wv;
    float acc[32];
    #pragma unroll
    for (int j=0;j<32;++j) acc[j] = wf[OFF_RT_B + c0 + j];
    for (int k=0;k<64;++k){
      float a = smf[(C_ES+k)*PF + lane];
      const float* wr = wf + OFF_RT_W + k*128 + c0;
      #pragma unroll
      for (int j=0;j<32;++j) acc[j] += a*wr[j];
    }
    #pragma unroll
    for (int j=0;j<32;++j) smf[(C_T + c0 + j)*PF + lane] = fsilu(acc[j]);
  }
  __syncthreads();

  // P2: scale_in (48 interleaved cols/lane, permuted rin_w) + scale_out (32+16)
  float sreg[48], souts[32], soutv[16];
  {
    #pragma unroll
    for (int i=0;i<48;++i) sreg[i] = 1.f + wf[OFF_RIN_B + 4*i + wv];
    #pragma unroll
    for (int j=0;j<32;++j) souts[j] = 1.f + wf[OFF_ROUT_B + 32*wv + j];
    #pragma unroll
    for (int t=0;t<16;++t) soutv[t] = 1.f + wf[OFF_ROUT_B + 128 + 16*wv + t];
    for (int k=0;k<128;++k){
      float a = smf[(C_T+k)*PF + lane];
      const float* wi = wf + OFF_RIN_W + k*192 + 48*wv;
      #pragma unroll
      for (int i=0;i<48;++i) sreg[i] += a*wi[i];
      const float* wo = wf + OFF_ROUT_W + k*192;
      #pragma unroll
      for (int j=0;j<32;++j) souts[j] += a*wo[32*wv + j];
      #pragma unroll
      for (int t=0;t<16;++t) soutv[t] += a*wo[128 + 16*wv + t];
    }
  }
  __syncthreads();   // trunk dead; C_XB free

  const float* hrow = h + (size_t)s_src[lane]*320;
  float msg_s[32], svv[16], mv[16][3];
  #pragma unroll
  for (int j=0;j<32;++j) msg_s[j]=0.f;
  #pragma unroll
  for (int t=0;t<16;++t){ svv[t]=0.f; mv[t][0]=0.f; mv[t][1]=0.f; mv[t][2]=0.f; }

  // ---- scalar chunk 1: x cols [0,64) ----
  #pragma unroll
  for (int i=0;i<16;++i){ int s = 4*i+wv; smf[(C_XB + s)*PF + lane] = hrow[s]*sreg[i]; }
  __syncthreads();
  for (int k=0;k<64;++k){
    float a = smf[(C_XB+k)*PF + lane];
    const float* w0p = wf + OFF_TP00 + k*128 + 32*wv;
    const float* w1p = wf + OFF_TP01 + k*64  + 16*wv;
    #pragma unroll
    for (int j=0;j<32;++j) msg_s[j] += a*w0p[j];
    #pragma unroll
    for (int t=0;t<16;++t) svv[t]  += a*w1p[t];
  }
  __syncthreads();
  // ---- scalar chunk 2: x cols [64,128) ----
  #pragma unroll
  for (int i=16;i<32;++i){ int s = 4*i+wv; smf[(C_XB + s-64)*PF + lane] = hrow[s]*sreg[i]; }
  __syncthreads();
  for (int k=0;k<64;++k){
    float a = smf[(C_XB+k)*PF + lane];
    const float* w0p = wf + OFF_TP00 + (64+k)*128 + 32*wv;
    const float* w1p = wf + OFF_TP01 + (64+k)*64  + 16*wv;
    #pragma unroll
    for (int j=0;j<32;++j) msg_s[j] += a*w0p[j];
    #pragma unroll
    for (int t=0;t<16;++t) svv[t]  += a*w1p[t];
  }
  __syncthreads();
  // ---- vector chunk 3: x cols [128,224), u in [0,32) ----
  #pragma unroll
  for (int i=32;i<40;++i){
    int s = 4*i+wv; int jg0 = 128 + 3*(s-128);
    #pragma unroll
    for (int d=0;d<3;++d) smf[(C_XB + jg0-128 + d)*PF + lane] = hrow[jg0+d]*sreg[i];
  }
  __syncthreads();
  { for (int ul=0; ul<32; ++ul){
      float x0 = smf[(C_XB + 3*ul+0)*PF + lane];
      float x1 = smf[(C_XB + 3*ul+1)*PF + lane];
      float x2 = smf[(C_XB + 3*ul+2)*PF + lane];
      const float* wr = wf + OFF_TP10 + ul*64 + 16*wv;
      #pragma unroll
      for (int t=0;t<16;++t){ float wt=wr[t]; mv[t][0]+=x0*wt; mv[t][1]+=x1*wt; mv[t][2]+=x2*wt; }
    }
    #pragma unroll
    for (int t=0;t<8;++t){
      int u = 8*wv + t;
      float d = (smf[(C_XB+3*u+0)*PF+lane]*y0 + smf[(C_XB+3*u+1)*PF+lane]*y1 +
                 smf[(C_XB+3*u+2)*PF+lane]*y2) * INV_SQ3f;
      smf[(C_DOT + u)*PF + lane] = d;
    } }
  __syncthreads();
  // ---- vector chunk 4: x cols [224,320), u in [32,64) ----
  #pragma unroll
  for (int i=40;i<48;++i){
    int s = 4*i+wv; int jg0 = 128 + 3*(s-128);
    #pragma unroll
    for (int d=0;d<3;++d) smf[(C_XB + jg0-224 + d)*PF + lane] = hrow[jg0+d]*sreg[i];
  }
  __syncthreads();
  { for (int ul=0; ul<32; ++ul){
      float x0 = smf[(C_XB + 3*ul+0)*PF + lane];
      float x1 = smf[(C_XB + 3*ul+1)*PF + lane];
      float x2 = smf[(C_XB + 3*ul+2)*PF + lane];
      const float* wr = wf + OFF_TP10 + (32+ul)*64 + 16*wv;
      #pragma unroll
      for (int t=0;t<16;++t){ float wt=wr[t]; mv[t][0]+=x0*wt; mv[t][1]+=x1*wt; mv[t][2]+=x2*wt; }
    }
    #pragma unroll
    for (int t=0;t<8;++t){
      int ul = 8*wv + t;
      float d = (smf[(C_XB+3*ul+0)*PF+lane]*y0 + smf[(C_XB+3*ul+1)*PF+lane]*y1 +
                 smf[(C_XB+3*ul+2)*PF+lane]*y2) * INV_SQ3f;
      smf[(C_DOT + 32 + ul)*PF + lane] = d;
    } }
  __syncthreads();

  // P4: rank-1 term
  #pragma unroll
  for (int t=0;t<16;++t){ mv[t][0]+=svv[t]*y0; mv[t][1]+=svv[t]*y1; mv[t][2]+=svv[t]*y2; }

  // P5: msg_s += dot @ tp_w11
  for (int k=0;k<64;++k){
    float a = smf[(C_DOT+k)*PF + lane];
    const float* wr = wf + OFF_TP11 + k*128 + 32*wv;
    #pragma unroll
    for (int j=0;j<32;++j) msg_s[j] += a*wr[j];
  }

  // P6: scale_out + silu + vn -> C_VN
  #pragma unroll
  for (int j=0;j<32;++j) msg_s[j] = fsilu(msg_s[j]*souts[j]);
  #pragma unroll
  for (int t=0;t<16;++t){
    mv[t][0]*=soutv[t]; mv[t][1]*=soutv[t]; mv[t][2]*=soutv[t];
    float vn = sqrtf(mv[t][0]*mv[t][0]+mv[t][1]*mv[t][1]+mv[t][2]*mv[t][2]+1e-12f);
    smf[(C_VN + 16*wv + t)*PF + lane] = vn;
  }
  __syncthreads();

  // P7: t1 = silu(vn@act_w1+b1) -> C_T1
  { float a1[16];
    #pragma unroll
    for (int t=0;t<16;++t) a1[t] = wf[OFF_ACT_B1 + 16*wv + t];
    for (int k=0;k<64;++k){
      float a = smf[(C_VN+k)*PF + lane];
      const float* wr = wf + OFF_ACT_W1 + k*64 + 16*wv;
      #pragma unroll
      for (int t=0;t<16;++t) a1[t] += a*wr[t];
    }
    #pragma unroll
    for (int t=0;t<16;++t) smf[(C_T1 + 16*wv + t)*PF + lane] = fsilu(a1[t]);
  }
  __syncthreads();
  // P8: g = sigmoid(t1@act_w2+b2); mv *= g
  { float gq[16];
    #pragma unroll
    for (int t=0;t<16;++t) gq[t] = wf[OFF_ACT_B2 + 16*wv + t];
    for (int k=0;k<64;++k){
      float a = smf[(C_T1+k)*PF + lane];
      const float* wr = wf + OFF_ACT_W2 + k*64 + 16*wv;
      #pragma unroll
      for (int t=0;t<16;++t) gq[t] += a*wr[t];
    }
    #pragma unroll
    for (int t=0;t<16;++t){ float g=fsig(gq[t]); mv[t][0]*=g; mv[t][1]*=g; mv[t][2]*=g; }
  }
  __syncthreads();

  // P10: ge = silu(es@gate_w1+b1) -> C_GE   (es still resident at C_ES)
  { float ge[16];
    #pragma unroll
    for (int t=0;t<16;++t) ge[t] = wf[OFF_GATE_B1 + 16*wv + t];
    for (int k=0;k<64;++k){
      float a = smf[(C_ES+k)*PF + lane];
      const float* wr = wf + OFF_GATE_W1 + k*64 + 16*wv;
      #pragma unroll
      for (int t=0;t<16;++t) ge[t] += a*wr[t];
    }
    #pragma unroll
    for (int t=0;t<16;++t) smf[(C_GE + 16*wv + t)*PF + lane] = fsilu(ge[t]);
  }
  __syncthreads();
  // P11: go = ge@gate_w2 + b2
  float vg[16];
  { float g0 = wf[OFF_GATE_B2];
    #pragma unroll
    for (int t=0;t<16;++t) vg[t] = wf[OFF_GATE_B2 + 1 + 16*wv + t];
    for (int k=0;k<64;++k){
      float a = smf[(C_GE+k)*PF + lane];
      const float* wr = wf + OFF_GATE_W2 + k*65;
      g0 += a*wr[0];
      #pragma unroll
      for (int t=0;t<16;++t) vg[t] += a*wr[1 + 16*wv + t];
    }
    #pragma unroll
    for (int t=0;t<16;++t) vg[t] = fsig(vg[t]);
    if (wv == 0){
      float sigma = __expf(wf[OFF_LSIG + etype[e]]);
      s_sgate[lane] = fsig(g0) * __expf(-edist[e]/sigma);
    }
  }
  __syncthreads();

  // P12: scatter
  { int dst = dst_idx[e];
    float sg = s_sgate[lane];
    #pragma unroll
    for (int j=0;j<32;++j) atomicAdd(acc_s + dst*128 + 32*wv + j, sg*msg_s[j]);
    if (wv == 0) atomicAdd(acc_sg + dst, sg);
    #pragma unroll
    for (int t=0;t<16;++t){
      int w = 16*wv + t;
      atomicAdd(acc_vg + dst*64 + w, vg[t]);
      atomicAdd(acc_v + dst*192 + w*3 + 0, vg[t]*mv[t][0]);
      atomicAdd(acc_v + dst*192 + w*3 + 1, vg[t]*mv[t][1]);
      atomicAdd(acc_v + dst*192 + w*3 + 2, vg[t]*mv[t][2]);
    }
  }
}

// ---------------- node kernel ----------------
// LDS: chunk region [0,96) ch + nvn [96,160) ch, pitch 65 (41.6 KB)
__launch_bounds__(256,2)
__global__ void k_node(const float* __restrict__ h, const float* __restrict__ wf,
                       const float* __restrict__ acc_s, const float* __restrict__ acc_sg,
                       const float* __restrict__ acc_vg, const float* __restrict__ acc_v,
                       float* __restrict__ out)
{
  __shared__ float smf[160*PF];
  const int tid  = threadIdx.x;
  const int lane = tid & 63;
  const int wv   = __builtin_amdgcn_readfirstlane(tid >> 6);
  const int n0   = blockIdx.x * 64;
  const int n    = n0 + lane;
  const int w0   = 16*wv;

  // agg / vn from accumulators; vn -> LDS [96,160)
  float agg[16][3], vnr[16], sva[16][3];
  #pragma unroll
  for (int t=0;t<16;++t){
    float inv = 1.f/(acc_vg[n*64 + w0 + t] + 1e-6f);
    agg[t][0] = acc_v[n*192 + (w0+t)*3 + 0]*inv;
    agg[t][1] = acc_v[n*192 + (w0+t)*3 + 1]*inv;
    agg[t][2] = acc_v[n*192 + (w0+t)*3 + 2]*inv;
    vnr[t] = sqrtf(agg[t][0]*agg[t][0]+agg[t][1]*agg[t][1]+agg[t][2]*agg[t][2]+1e-12f);
    smf[(96 + w0 + t)*PF + lane] = vnr[t];
    sva[t][0]=0.f; sva[t][1]=0.f; sva[t][2]=0.f;
  }

  float outs[32];
  #pragma unroll
  for (int j=0;j<32;++j) outs[j] = wf[OFF_SELF_BS + 32*wv + j];

  // scalar chunks (h cols [0,64), [64,128))
  for (int cc=0; cc<2; ++cc){
    for (int lin=tid; lin<1024; lin+=256){
      int row = lin>>4, c4 = lin&15;
      float4 v = reinterpret_cast<const float4*>(h)[(n0+row)*80 + cc*16 + c4];
      smf[(c4*4+0)*PF + row] = v.x;
      smf[(c4*4+1)*PF + row] = v.y;
      smf[(c4*4+2)*PF + row] = v.z;
      smf[(c4*4+3)*PF + row] = v.w;
    }
    __syncthreads();
    for (int k=0;k<64;++k){
      float a = smf[k*PF + lane];
      const float* wr = wf + OFF_SELF_WS + (cc*64+k)*128 + 32*wv;
      #pragma unroll
      for (int j=0;j<32;++j) outs[j] += a*wr[j];
    }
    __syncthreads();
  }
  // vector chunks (h cols [128,224), [224,320))
  for (int cc=0; cc<2; ++cc){
    for (int lin=tid; lin<1536; lin+=256){
      int row = lin/24, c6 = lin%24;
      float4 v = reinterpret_cast<const float4*>(h)[(n0+row)*80 + 32 + cc*24 + c6];
      smf[(c6*4+0)*PF + row] = v.x;
      smf[(c6*4+1)*PF + row] = v.y;
      smf[(c6*4+2)*PF + row] = v.z;
      smf[(c6*4+3)*PF + row] = v.w;
    }
    __syncthreads();
    for (int ul=0; ul<32; ++ul){
      float x0 = smf[(3*ul+0)*PF + lane];
      float x1 = smf[(3*ul+1)*PF + lane];
      float x2 = smf[(3*ul+2)*PF + lane];
      const float* wr = wf + OFF_SELF_WV + (cc*32+ul)*64 + w0;
      #pragma unroll
      for (int t=0;t<16;++t){ float wt=wr[t]; sva[t][0]+=x0*wt; sva[t][1]+=x1*wt; sva[t][2]+=x2*wt; }
    }
    __syncthreads();
  }

  // vr: rv = vn@vr_w + vr_b  (reads nvn region)
  float rv[16];
  #pragma unroll
  for (int t=0;t<16;++t) rv[t] = wf[OFF_VR_B + w0 + t];
  for (int k=0;k<64;++k){
    float a = smf[(96+k)*PF + lane];
    const float* wr = wf + OFF_VR_W + k*64 + w0;
    #pragma unroll
    for (int t=0;t<16;++t) rv[t] += a*wr[t];
  }

  // scalar aggregate part
  { float inv = 1.f/(acc_sg[n] + 1e-6f);
    #pragma unroll
    for (int j=0;j<32;++j) outs[j] += acc_s[n*128 + 32*wv + j]*inv;
  }

  // stores: per-lane contiguous float4 runs
  float* orow = out + (size_t)n*320;
  { float4* o4 = reinterpret_cast<float4*>(orow + 32*wv);
    #pragma unroll
    for (int j=0;j<8;++j){
      float4 v; v.x=outs[4*j]; v.y=outs[4*j+1]; v.z=outs[4*j+2]; v.w=outs[4*j+3];
      o4[j] = v;
    }
  }
  { float vbuf[48];
    #pragma unroll
    for (int t=0;t<16;++t){
      float sc = rv[t]/(vnr[t]+1e-6f);
      vbuf[t*3+0] = agg[t][0]*sc + sva[t][0];
      vbuf[t*3+1] = agg[t][1]*sc + sva[t][1];
      vbuf[t*3+2] = agg[t][2]*sc + sva[t][2];
    }
    float4* o4 = reinterpret_cast<float4*>(orow + 128 + 48*wv);
    #pragma unroll
    for (int j=0;j<12;++j){
      float4 v; v.x=vbuf[4*j]; v.y=vbuf[4*j+1]; v.z=vbuf[4*j+2]; v.w=vbuf[4*j+3];
      o4[j] = v;
    }
  }
}

// ---------------- launch ----------------
extern "C" void kernel_launch(void* const* d_in, const int* in_sizes, int n_in,
                              void* d_out, int out_size, void* d_ws, size_t ws_size,
                              hipStream_t stream) {
  const float* h     = (const float*)d_in[0];
  const float* evec  = (const float*)d_in[1];
  const float* es    = (const float*)d_in[2];
  const float* edist = (const float*)d_in[3];
  const int* srcI    = (const int*)d_in[4];
  const int* dstI    = (const int*)d_in[5];
  const int* etyp    = (const int*)d_in[6];

  float* wsf    = (float*)d_ws;
  float* acc_s  = wsf + ACC_S_OFF;
  float* acc_sg = wsf + ACC_SG_OFF;
  float* acc_vg = wsf + ACC_VG_OFF;
  float* acc_v  = wsf + ACC_V_OFF;

  WCopy wc;
  const int ns[24]  = {8192,128,24576,192,24576,192,16384,8192,4096,8192,4096,64,4096,64,
                       4096,64,4160,65,10,4096,64,16384,128,4096};
  const int offs[24]= {OFF_RT_W,OFF_RT_B,OFF_RIN_W,OFF_RIN_B,OFF_ROUT_W,OFF_ROUT_B,
                       OFF_TP00,OFF_TP01,OFF_TP10,OFF_TP11,OFF_ACT_W1,OFF_ACT_B1,
                       OFF_ACT_W2,OFF_ACT_B2,OFF_GATE_W1,OFF_GATE_B1,OFF_GATE_W2,OFF_GATE_B2,
                       OFF_LSIG,OFF_VR_W,OFF_VR_B,OFF_SELF_WS,OFF_SELF_BS,OFF_SELF_WV};
  for (int a=0;a<24;++a){ wc.src[a] = (const float*)d_in[8+a]; wc.n[a]=ns[a]; wc.off[a]=offs[a]; }
  hipLaunchKernelGGL(k_copy, dim3(533), dim3(256), 0, stream, wc, wsf);

  { int nz = ACC_END - ACC_S_OFF;
    hipLaunchKernelGGL(k_zero, dim3((nz+255)/256), dim3(256), 0, stream, acc_s, nz); }

  hipLaunchKernelGGL(k_edge, dim3(N_EDGES/64), dim3(256), 0, stream,
                     h, evec, es, edist, srcI, dstI, etyp, wsf,
                     acc_s, acc_sg, acc_vg, acc_v);
  hipLaunchKernelGGL(k_node, dim3(N_NODES/64), dim3(256), 0, stream,
                     h, wsf, acc_s, acc_sg, acc_vg, acc_v, (float*)d_out);
}

// Round 6
// 2591.248 us; speedup vs baseline: 2.3076x; 2.3076x over previous
//
#include <hip/hip_runtime.h>

typedef unsigned int u32;

#define N_NODES 32768
#define N_EDGES 262144
#define PF 65   // LDS pitch (floats): 64 edges + 1 pad

// ---------- fp32 weight buffer layout (float offsets in d_ws) ----------
enum : int {
  OFF_RT_W   = 0,       // [64,128]
  OFF_RT_B   = 8192,    // [128]
  OFF_RIN_W  = 8320,    // [128,192]  (stored PERMUTED: col c -> (c%4)*48 + c/4)
  OFF_RIN_B  = 32896,   // [192]
  OFF_ROUT_W = 33088,   // [128,192]
  OFF_ROUT_B = 57664,   // [192]
  OFF_TP00   = 57856,   // [128,128]
  OFF_TP01   = 74240,   // [128,64]
  OFF_TP10   = 82432,   // [64,64]
  OFF_TP11   = 86528,   // [64,128]
  OFF_ACT_W1 = 94720,   // [64,64]
  OFF_ACT_B1 = 98816,   // [64]
  OFF_ACT_W2 = 98880,   // [64,64]
  OFF_ACT_B2 = 102976,  // [64]
  OFF_GATE_W1= 103040,  // [64,64]
  OFF_GATE_B1= 107136,  // [64]
  OFF_GATE_W2= 107200,  // [64,65]
  OFF_GATE_B2= 111360,  // [65]
  OFF_LSIG   = 111428,  // [10]
  OFF_VR_W   = 111440,  // [64,64]
  OFF_VR_B   = 115536,  // [64]
  OFF_SELF_WS= 115600,  // [128,128]
  OFF_SELF_BS= 131984,  // [128]
  OFF_SELF_WV= 132112,  // [64,64]
  NWF        = 136208
};
enum : int {
  ACC_S_OFF  = NWF,
  ACC_SG_OFF = ACC_S_OFF + N_NODES*128,
  ACC_VG_OFF = ACC_SG_OFF + N_NODES,
  ACC_V_OFF  = ACC_VG_OFF + N_NODES*64,
  ACC_END    = ACC_V_OFF + N_NODES*192
};

__device__ __forceinline__ float fsilu(float x){ return x/(1.f+__expf(-x)); }
__device__ __forceinline__ float fsig (float x){ return 1.f/(1.f+__expf(-x)); }

#define SQ3f     1.7320508075688772f
#define INV_SQ3f 0.5773502691896258f

__global__ void k_zero(float* __restrict__ p, int n){
  int t = blockIdx.x*256 + threadIdx.x;
  if (t < n) p[t] = 0.f;
}

// weight copy; tensor index 2 (rin_w) gets its columns permuted so that
// wave wv's owned cols {4i+wv} land contiguously at [48*wv, 48*wv+48)
struct WCopy { const float* src[24]; int n[24]; int off[24]; };

__global__ void k_copy(WCopy w, float* __restrict__ dst){
  int t = blockIdx.x*256 + threadIdx.x;
  for (int a=0;a<24;++a){
    int n = w.n[a];
    if (t < n){
      if (a == 2){
        int k = t/192, c = t%192;
        dst[w.off[a] + k*192 + (c&3)*48 + (c>>2)] = w.src[a][t];
      } else {
        dst[w.off[a]+t] = w.src[a][t];
      }
      return;
    }
    t -= n;
  }
}

// ---------------- edge kernel ----------------
// LDS arena: 224 channels x pitch 65 floats (58.2 KB)
constexpr int C_ES=0, C_T=64, C_XB=64, C_DOT=160, C_VN=64, C_T1=128, C_GE=160;

__launch_bounds__(256,2)
__global__ void k_edge(const float* __restrict__ h, const float* __restrict__ evec,
                       const float* __restrict__ es_g, const float* __restrict__ edist,
                       const int* __restrict__ src_idx, const int* __restrict__ dst_idx,
                       const int* __restrict__ etype, const float* __restrict__ wf,
                       float* __restrict__ acc_s, float* __restrict__ acc_sg,
                       float* __restrict__ acc_vg, float* __restrict__ acc_v)
{
  __shared__ float smf[224*PF];
  __shared__ float s_sgate[64];
  __shared__ int   s_src[64];
  __shared__ int   s_dst[64];

  const int tid  = threadIdx.x;
  const int lane = tid & 63;
  const int wv   = __builtin_amdgcn_readfirstlane(tid >> 6);
  const int e0   = blockIdx.x * 64;
  const int e    = e0 + lane;

  if (tid < 64) s_src[tid] = src_idx[e0 + tid];
  else if (tid < 128) s_dst[tid-64] = dst_idx[e0 + tid-64];

  float y0,y1,y2;
  { float vx=evec[e*3], vy=evec[e*3+1], vz=evec[e*3+2];
    float rn = SQ3f * rsqrtf(vx*vx+vy*vy+vz*vz+1e-12f);
    y0=vx*rn; y1=vy*rn; y2=vz*rn; }

  // P0: stage edge_scalars (fp32, coalesced float4)
  for (int lin=tid; lin<1024; lin+=256){
    int row = lin>>4, c4 = lin&15;
    float4 v = reinterpret_cast<const float4*>(es_g)[(e0+row)*16 + c4];
    smf[(C_ES + c4*4+0)*PF + row] = v.x;
    smf[(C_ES + c4*4+1)*PF + row] = v.y;
    smf[(C_ES + c4*4+2)*PF + row] = v.z;
    smf[(C_ES + c4*4+3)*PF + row] = v.w;
  }
  __syncthreads();

  // P1: trunk = silu(es @ rt_w + rt_b), 32 ch/wave -> C_T
  { const int c0 = 32*wv;
    float acc[32];
    #pragma unroll
    for (int j=0;j<32;++j) acc[j] = wf[OFF_RT_B + c0 + j];
    for (int k=0;k<64;++k){
      float a = smf[(C_ES+k)*PF + lane];
      const float* wr = wf + OFF_RT_W + k*128 + c0;
      #pragma unroll
      for (int j=0;j<32;++j) acc[j] += a*wr[j];
    }
    #pragma unroll
    for (int j=0;j<32;++j) smf[(C_T + c0 + j)*PF + lane] = fsilu(acc[j]);
  }
  __syncthreads();

  // P2: scale_in (48 interleaved cols/lane, permuted rin_w) + scale_out (32+16)
  float sreg[48], souts[32], soutv[16];
  {
    #pragma unroll
    for (int i=0;i<48;++i) sreg[i] = 1.f + wf[OFF_RIN_B + 4*i + wv];
    #pragma unroll
    for (int j=0;j<32;++j) souts[j] = 1.f + wf[OFF_ROUT_B + 32*wv + j];
    #pragma unroll
    for (int t=0;t<16;++t) soutv[t] = 1.f + wf[OFF_ROUT_B + 128 + 16*wv + t];
    for (int k=0;k<128;++k){
      float a = smf[(C_T+k)*PF + lane];
      const float* wi = wf + OFF_RIN_W + k*192 + 48*wv;
      #pragma unroll
      for (int i=0;i<48;++i) sreg[i] += a*wi[i];
      const float* wo = wf + OFF_ROUT_W + k*192;
      #pragma unroll
      for (int j=0;j<32;++j) souts[j] += a*wo[32*wv + j];
      #pragma unroll
      for (int t=0;t<16;++t) soutv[t] += a*wo[128 + 16*wv + t];
    }
  }
  __syncthreads();   // trunk dead; C_XB free

  const float* hrow = h + (size_t)s_src[lane]*320;
  float msg_s[32], svv[16], mv[16][3];
  #pragma unroll
  for (int j=0;j<32;++j) msg_s[j]=0.f;
  #pragma unroll
  for (int t=0;t<16;++t){ svv[t]=0.f; mv[t][0]=0.f; mv[t][1]=0.f; mv[t][2]=0.f; }

  // ---- scalar chunk 1: x cols [0,64) ----
  #pragma unroll
  for (int i=0;i<16;++i){ int s = 4*i+wv; smf[(C_XB + s)*PF + lane] = hrow[s]*sreg[i]; }
  __syncthreads();
  for (int k=0;k<64;++k){
    float a = smf[(C_XB+k)*PF + lane];
    const float* w0p = wf + OFF_TP00 + k*128 + 32*wv;
    const float* w1p = wf + OFF_TP01 + k*64  + 16*wv;
    #pragma unroll
    for (int j=0;j<32;++j) msg_s[j] += a*w0p[j];
    #pragma unroll
    for (int t=0;t<16;++t) svv[t]  += a*w1p[t];
  }
  __syncthreads();
  // ---- scalar chunk 2: x cols [64,128) ----
  #pragma unroll
  for (int i=16;i<32;++i){ int s = 4*i+wv; smf[(C_XB + s-64)*PF + lane] = hrow[s]*sreg[i]; }
  __syncthreads();
  for (int k=0;k<64;++k){
    float a = smf[(C_XB+k)*PF + lane];
    const float* w0p = wf + OFF_TP00 + (64+k)*128 + 32*wv;
    const float* w1p = wf + OFF_TP01 + (64+k)*64  + 16*wv;
    #pragma unroll
    for (int j=0;j<32;++j) msg_s[j] += a*w0p[j];
    #pragma unroll
    for (int t=0;t<16;++t) svv[t]  += a*w1p[t];
  }
  __syncthreads();
  // ---- vector chunk 3: x cols [128,224), u in [0,32) ----
  #pragma unroll
  for (int i=32;i<40;++i){
    int s = 4*i+wv; int jg0 = 128 + 3*(s-128);
    #pragma unroll
    for (int d=0;d<3;++d) smf[(C_XB + jg0-128 + d)*PF + lane] = hrow[jg0+d]*sreg[i];
  }
  __syncthreads();
  { for (int ul=0; ul<32; ++ul){
      float x0 = smf[(C_XB + 3*ul+0)*PF + lane];
      float x1 = smf[(C_XB + 3*ul+1)*PF + lane];
      float x2 = smf[(C_XB + 3*ul+2)*PF + lane];
      const float* wr = wf + OFF_TP10 + ul*64 + 16*wv;
      #pragma unroll
      for (int t=0;t<16;++t){ float wt=wr[t]; mv[t][0]+=x0*wt; mv[t][1]+=x1*wt; mv[t][2]+=x2*wt; }
    }
    #pragma unroll
    for (int t=0;t<8;++t){
      int u = 8*wv + t;
      float d = (smf[(C_XB+3*u+0)*PF+lane]*y0 + smf[(C_XB+3*u+1)*PF+lane]*y1 +
                 smf[(C_XB+3*u+2)*PF+lane]*y2) * INV_SQ3f;
      smf[(C_DOT + u)*PF + lane] = d;
    } }
  __syncthreads();
  // ---- vector chunk 4: x cols [224,320), u in [32,64) ----
  #pragma unroll
  for (int i=40;i<48;++i){
    int s = 4*i+wv; int jg0 = 128 + 3*(s-128);
    #pragma unroll
    for (int d=0;d<3;++d) smf[(C_XB + jg0-224 + d)*PF + lane] = hrow[jg0+d]*sreg[i];
  }
  __syncthreads();
  { for (int ul=0; ul<32; ++ul){
      float x0 = smf[(C_XB + 3*ul+0)*PF + lane];
      float x1 = smf[(C_XB + 3*ul+1)*PF + lane];
      float x2 = smf[(C_XB + 3*ul+2)*PF + lane];
      const float* wr = wf + OFF_TP10 + (32+ul)*64 + 16*wv;
      #pragma unroll
      for (int t=0;t<16;++t){ float wt=wr[t]; mv[t][0]+=x0*wt; mv[t][1]+=x1*wt; mv[t][2]+=x2*wt; }
    }
    #pragma unroll
    for (int t=0;t<8;++t){
      int ul = 8*wv + t;
      float d = (smf[(C_XB+3*ul+0)*PF+lane]*y0 + smf[(C_XB+3*ul+1)*PF+lane]*y1 +
                 smf[(C_XB+3*ul+2)*PF+lane]*y2) * INV_SQ3f;
      smf[(C_DOT + 32 + ul)*PF + lane] = d;
    } }
  __syncthreads();

  // P4: rank-1 term
  #pragma unroll
  for (int t=0;t<16;++t){ mv[t][0]+=svv[t]*y0; mv[t][1]+=svv[t]*y1; mv[t][2]+=svv[t]*y2; }

  // P5: msg_s += dot @ tp_w11
  for (int k=0;k<64;++k){
    float a = smf[(C_DOT+k)*PF + lane];
    const float* wr = wf + OFF_TP11 + k*128 + 32*wv;
    #pragma unroll
    for (int j=0;j<32;++j) msg_s[j] += a*wr[j];
  }

  // P6: scale_out + silu + vn -> C_VN
  #pragma unroll
  for (int j=0;j<32;++j) msg_s[j] = fsilu(msg_s[j]*souts[j]);
  #pragma unroll
  for (int t=0;t<16;++t){
    mv[t][0]*=soutv[t]; mv[t][1]*=soutv[t]; mv[t][2]*=soutv[t];
    float vn = sqrtf(mv[t][0]*mv[t][0]+mv[t][1]*mv[t][1]+mv[t][2]*mv[t][2]+1e-12f);
    smf[(C_VN + 16*wv + t)*PF + lane] = vn;
  }
  __syncthreads();

  // P7: t1 = silu(vn@act_w1+b1) -> C_T1
  { float a1[16];
    #pragma unroll
    for (int t=0;t<16;++t) a1[t] = wf[OFF_ACT_B1 + 16*wv + t];
    for (int k=0;k<64;++k){
      float a = smf[(C_VN+k)*PF + lane];
      const float* wr = wf + OFF_ACT_W1 + k*64 + 16*wv;
      #pragma unroll
      for (int t=0;t<16;++t) a1[t] += a*wr[t];
    }
    #pragma unroll
    for (int t=0;t<16;++t) smf[(C_T1 + 16*wv + t)*PF + lane] = fsilu(a1[t]);
  }
  __syncthreads();
  // P8: g = sigmoid(t1@act_w2+b2); mv *= g
  { float gq[16];
    #pragma unroll
    for (int t=0;t<16;++t) gq[t] = wf[OFF_ACT_B2 + 16*wv + t];
    for (int k=0;k<64;++k){
      float a = smf[(C_T1+k)*PF + lane];
      const float* wr = wf + OFF_ACT_W2 + k*64 + 16*wv;
      #pragma unroll
      for (int t=0;t<16;++t) gq[t] += a*wr[t];
    }
    #pragma unroll
    for (int t=0;t<16;++t){ float g=fsig(gq[t]); mv[t][0]*=g; mv[t][1]*=g; mv[t][2]*=g; }
  }
  __syncthreads();

  // P10: ge = silu(es@gate_w1+b1) -> C_GE   (es still resident at C_ES)
  { float ge[16];
    #pragma unroll
    for (int t=0;t<16;++t) ge[t] = wf[OFF_GATE_B1 + 16*wv + t];
    for (int k=0;k<64;++k){
      float a = smf[(C_ES+k)*PF + lane];
      const float* wr = wf + OFF_GATE_W1 + k*64 + 16*wv;
      #pragma unroll
      for (int t=0;t<16;++t) ge[t] += a*wr[t];
    }
    #pragma unroll
    for (int t=0;t<16;++t) smf[(C_GE + 16*wv + t)*PF + lane] = fsilu(ge[t]);
  }
  __syncthreads();
  // P11: go = ge@gate_w2 + b2
  float vg[16];
  { float g0 = wf[OFF_GATE_B2];
    #pragma unroll
    for (int t=0;t<16;++t) vg[t] = wf[OFF_GATE_B2 + 1 + 16*wv + t];
    for (int k=0;k<64;++k){
      float a = smf[(C_GE+k)*PF + lane];
      const float* wr = wf + OFF_GATE_W2 + k*65;
      g0 += a*wr[0];
      #pragma unroll
      for (int t=0;t<16;++t) vg[t] += a*wr[1 + 16*wv + t];
    }
    #pragma unroll
    for (int t=0;t<16;++t) vg[t] = fsig(vg[t]);
    if (wv == 0){
      float sigma = __expf(wf[OFF_LSIG + etype[e]]);
      s_sgate[lane] = fsig(g0) * __expf(-edist[e]/sigma);
    }
  }
  __syncthreads();

  // ===== P12: COALESCED scatter via LDS transpose =====
  // Phase A: sg*msg_s  (128 channels)
  { float sg = s_sgate[lane];
    #pragma unroll
    for (int j=0;j<32;++j) smf[(32*wv + j)*PF + lane] = sg*msg_s[j];
  }
  __syncthreads();
  for (int lin=tid; lin<8192; lin+=256){
    int row = lin >> 7, ch = lin & 127;
    atomicAdd(acc_s + (size_t)s_dst[row]*128 + ch, smf[ch*PF + row]);
  }
  __syncthreads();
  // Phase B: vg*mv  (192 channels)
  #pragma unroll
  for (int t=0;t<16;++t){
    int w = 16*wv + t;
    smf[(3*w+0)*PF + lane] = vg[t]*mv[t][0];
    smf[(3*w+1)*PF + lane] = vg[t]*mv[t][1];
    smf[(3*w+2)*PF + lane] = vg[t]*mv[t][2];
  }
  __syncthreads();
  for (int lin=tid; lin<12288; lin+=256){
    int row = lin / 192, ch = lin % 192;
    atomicAdd(acc_v + (size_t)s_dst[row]*192 + ch, smf[ch*PF + row]);
  }
  __syncthreads();
  // Phase C: vg (64 ch) + sg (1)
  #pragma unroll
  for (int t=0;t<16;++t) smf[(16*wv + t)*PF + lane] = vg[t];
  __syncthreads();
  for (int lin=tid; lin<4096; lin+=256){
    int row = lin >> 6, ch = lin & 63;
    atomicAdd(acc_vg + (size_t)s_dst[row]*64 + ch, smf[ch*PF + row]);
  }
  if (tid < 64) atomicAdd(acc_sg + s_dst[tid], s_sgate[tid]);
}

// ---------------- node kernel ----------------
__launch_bounds__(256,2)
__global__ void k_node(const float* __restrict__ h, const float* __restrict__ wf,
                       const float* __restrict__ acc_s, const float* __restrict__ acc_sg,
                       const float* __restrict__ acc_vg, const float* __restrict__ acc_v,
                       float* __restrict__ out)
{
  __shared__ float smf[160*PF];
  const int tid  = threadIdx.x;
  const int lane = tid & 63;
  const int wv   = __builtin_amdgcn_readfirstlane(tid >> 6);
  const int n0   = blockIdx.x * 64;
  const int n    = n0 + lane;
  const int w0   = 16*wv;

  float agg[16][3], vnr[16], sva[16][3];
  #pragma unroll
  for (int t=0;t<16;++t){
    float inv = 1.f/(acc_vg[n*64 + w0 + t] + 1e-6f);
    agg[t][0] = acc_v[n*192 + (w0+t)*3 + 0]*inv;
    agg[t][1] = acc_v[n*192 + (w0+t)*3 + 1]*inv;
    agg[t][2] = acc_v[n*192 + (w0+t)*3 + 2]*inv;
    vnr[t] = sqrtf(agg[t][0]*agg[t][0]+agg[t][1]*agg[t][1]+agg[t][2]*agg[t][2]+1e-12f);
    smf[(96 + w0 + t)*PF + lane] = vnr[t];
    sva[t][0]=0.f; sva[t][1]=0.f; sva[t][2]=0.f;
  }

  float outs[32];
  #pragma unroll
  for (int j=0;j<32;++j) outs[j] = wf[OFF_SELF_BS + 32*wv + j];

  for (int cc=0; cc<2; ++cc){
    for (int lin=tid; lin<1024; lin+=256){
      int row = lin>>4, c4 = lin&15;
      float4 v = reinterpret_cast<const float4*>(h)[(n0+row)*80 + cc*16 + c4];
      smf[(c4*4+0)*PF + row] = v.x;
      smf[(c4*4+1)*PF + row] = v.y;
      smf[(c4*4+2)*PF + row] = v.z;
      smf[(c4*4+3)*PF + row] = v.w;
    }
    __syncthreads();
    for (int k=0;k<64;++k){
      float a = smf[k*PF + lane];
      const float* wr = wf + OFF_SELF_WS + (cc*64+k)*128 + 32*wv;
      #pragma unroll
      for (int j=0;j<32;++j) outs[j] += a*wr[j];
    }
    __syncthreads();
  }
  for (int cc=0; cc<2; ++cc){
    for (int lin=tid; lin<1536; lin+=256){
      int row = lin/24, c6 = lin%24;
      float4 v = reinterpret_cast<const float4*>(h)[(n0+row)*80 + 32 + cc*24 + c6];
      smf[(c6*4+0)*PF + row] = v.x;
      smf[(c6*4+1)*PF + row] = v.y;
      smf[(c6*4+2)*PF + row] = v.z;
      smf[(c6*4+3)*PF + row] = v.w;
    }
    __syncthreads();
    for (int ul=0; ul<32; ++ul){
      float x0 = smf[(3*ul+0)*PF + lane];
      float x1 = smf[(3*ul+1)*PF + lane];
      float x2 = smf[(3*ul+2)*PF + lane];
      const float* wr = wf + OFF_SELF_WV + (cc*32+ul)*64 + w0;
      #pragma unroll
      for (int t=0;t<16;++t){ float wt=wr[t]; sva[t][0]+=x0*wt; sva[t][1]+=x1*wt; sva[t][2]+=x2*wt; }
    }
    __syncthreads();
  }

  float rv[16];
  #pragma unroll
  for (int t=0;t<16;++t) rv[t] = wf[OFF_VR_B + w0 + t];
  for (int k=0;k<64;++k){
    float a = smf[(96+k)*PF + lane];
    const float* wr = wf + OFF_VR_W + k*64 + w0;
    #pragma unroll
    for (int t=0;t<16;++t) rv[t] += a*wr[t];
  }

  { float inv = 1.f/(acc_sg[n] + 1e-6f);
    #pragma unroll
    for (int j=0;j<32;++j) outs[j] += acc_s[n*128 + 32*wv + j]*inv;
  }

  float* orow = out + (size_t)n*320;
  { float4* o4 = reinterpret_cast<float4*>(orow + 32*wv);
    #pragma unroll
    for (int j=0;j<8;++j){
      float4 v; v.x=outs[4*j]; v.y=outs[4*j+1]; v.z=outs[4*j+2]; v.w=outs[4*j+3];
      o4[j] = v;
    }
  }
  { float vbuf[48];
    #pragma unroll
    for (int t=0;t<16;++t){
      float sc = rv[t]/(vnr[t]+1e-6f);
      vbuf[t*3+0] = agg[t][0]*sc + sva[t][0];
      vbuf[t*3+1] = agg[t][1]*sc + sva[t][1];
      vbuf[t*3+2] = agg[t][2]*sc + sva[t][2];
    }
    float4* o4 = reinterpret_cast<float4*>(orow + 128 + 48*wv);
    #pragma unroll
    for (int j=0;j<12;++j){
      float4 v; v.x=vbuf[4*j]; v.y=vbuf[4*j+1]; v.z=vbuf[4*j+2]; v.w=vbuf[4*j+3];
      o4[j] = v;
    }
  }
}

// ---------------- launch ----------------
extern "C" void kernel_launch(void* const* d_in, const int* in_sizes, int n_in,
                              void* d_out, int out_size, void* d_ws, size_t ws_size,
                              hipStream_t stream) {
  const float* h     = (const float*)d_in[0];
  const float* evec  = (const float*)d_in[1];
  const float* es    = (const float*)d_in[2];
  const float* edist = (const float*)d_in[3];
  const int* srcI    = (const int*)d_in[4];
  const int* dstI    = (const int*)d_in[5];
  const int* etyp    = (const int*)d_in[6];

  float* wsf    = (float*)d_ws;
  float* acc_s  = wsf + ACC_S_OFF;
  float* acc_sg = wsf + ACC_SG_OFF;
  float* acc_vg = wsf + ACC_VG_OFF;
  float* acc_v  = wsf + ACC_V_OFF;

  WCopy wc;
  const int ns[24]  = {8192,128,24576,192,24576,192,16384,8192,4096,8192,4096,64,4096,64,
                       4096,64,4160,65,10,4096,64,16384,128,4096};
  const int offs[24]= {OFF_RT_W,OFF_RT_B,OFF_RIN_W,OFF_RIN_B,OFF_ROUT_W,OFF_ROUT_B,
                       OFF_TP00,OFF_TP01,OFF_TP10,OFF_TP11,OFF_ACT_W1,OFF_ACT_B1,
                       OFF_ACT_W2,OFF_ACT_B2,OFF_GATE_W1,OFF_GATE_B1,OFF_GATE_W2,OFF_GATE_B2,
                       OFF_LSIG,OFF_VR_W,OFF_VR_B,OFF_SELF_WS,OFF_SELF_BS,OFF_SELF_WV};
  for (int a=0;a<24;++a){ wc.src[a] = (const float*)d_in[8+a]; wc.n[a]=ns[a]; wc.off[a]=offs[a]; }
  hipLaunchKernelGGL(k_copy, dim3(533), dim3(256), 0, stream, wc, wsf);

  { int nz = ACC_END - ACC_S_OFF;
    hipLaunchKernelGGL(k_zero, dim3((nz+255)/256), dim3(256), 0, stream, acc_s, nz); }

  hipLaunchKernelGGL(k_edge, dim3(N_EDGES/64), dim3(256), 0, stream,
                     h, evec, es, edist, srcI, dstI, etyp, wsf,
                     acc_s, acc_sg, acc_vg, acc_v);
  hipLaunchKernelGGL(k_node, dim3(N_NODES/64), dim3(256), 0, stream,
                     h, wsf, acc_s, acc_sg, acc_vg, acc_v, (float*)d_out);
}